// Round 1
// baseline (1029.598 us; speedup 1.0000x reference)
//
#include <hip/hip_runtime.h>

#define NN 100000
#define NE 1600000

// ---------------- degree / normalization ----------------
__global__ __launch_bounds__(256) void k_count(const int* __restrict__ dst,
                                               float* __restrict__ cnt) {
  int i = blockIdx.x * 256 + threadIdx.x;
  if (i < NE) atomicAdd(&cnt[dst[i]], 1.0f);
}

__global__ __launch_bounds__(256) void k_rsqrt_deg(float* __restrict__ dis) {
  int i = blockIdx.x * 256 + threadIdx.x;
  if (i < NN) dis[i] = rsqrtf(dis[i] + 1.0f);  // deg = count + 1 (self loop)
}

// ---------------- fused 64x64 GEMM + self-loop/bias init ----------------
// h[row]   = (RELU_IN ? relu(in[row]) : in[row]) @ W
// agg[row] = h[row] * dis[row]^2 + b      (agg may alias in: same-index RAW only)
template <bool RELU_IN>
__global__ __launch_bounds__(256) void k_mm64(const float* __restrict__ in,
                                              const float* __restrict__ W,
                                              const float* __restrict__ b,
                                              const float* __restrict__ dis,
                                              float* __restrict__ h,
                                              float* __restrict__ agg) {
  __shared__ float Wl[64 * 64];
  for (int i = threadIdx.x; i < 64 * 64; i += 256) Wl[i] = W[i];
  __syncthreads();
  const int lane = threadIdx.x & 63;
  const int gw = (blockIdx.x * 256 + threadIdx.x) >> 6;
  const int nw = gridDim.x * 4;
  const float bl = b[lane];
  for (int row = gw; row < NN; row += nw) {
    float v = in[row * 64 + lane];
    if (RELU_IN) v = fmaxf(v, 0.0f);
    float acc = 0.0f;
#pragma unroll
    for (int k = 0; k < 64; ++k)
      acc = fmaf(__shfl(v, k), Wl[k * 64 + lane], acc);
    h[row * 64 + lane] = acc;
    const float d = dis[row];
    agg[row * 64 + lane] = fmaf(acc, d * d, bl);
  }
}

// ---------------- edge scatter: agg[dst] += h[src] * dis[src]*dis[dst] ----
__global__ __launch_bounds__(256) void k_scatter(const int* __restrict__ src,
                                                 const int* __restrict__ dst,
                                                 const float* __restrict__ dis,
                                                 const float* __restrict__ h,
                                                 float* __restrict__ agg) {
  const int lane = threadIdx.x & 63;
  const int gw = (blockIdx.x * 256 + threadIdx.x) >> 6;
  const int nw = gridDim.x * 4;
  for (int e = gw; e < NE; e += nw) {
    const int s = src[e];
    const int t = dst[e];
    const float norm = dis[s] * dis[t];
    const float val = h[s * 64 + lane] * norm;
    atomicAdd(&agg[t * 64 + lane], val);
  }
}

// ---------------- fused head: relu -> [64x128] dense -> relu -> [128x2] ----
__global__ __launch_bounds__(256) void k_head(const float* __restrict__ agg,
                                              const float* __restrict__ Wd,
                                              const float* __restrict__ bd,
                                              const float* __restrict__ Wo,
                                              const float* __restrict__ bo,
                                              float* __restrict__ out) {
  __shared__ float Wdl[64 * 128];  // 32 KiB
  __shared__ float Wol[256];       // 128x2
  for (int i = threadIdx.x; i < 64 * 128; i += 256) Wdl[i] = Wd[i];
  if (threadIdx.x < 256) Wol[threadIdx.x] = Wo[threadIdx.x];
  __syncthreads();
  const int lane = threadIdx.x & 63;
  const int gw = (blockIdx.x * 256 + threadIdx.x) >> 6;
  const int nw = gridDim.x * 4;
  const float bd0 = bd[lane], bd1 = bd[lane + 64];
  const float bo0 = bo[0], bo1 = bo[1];
  for (int row = gw; row < NN; row += nw) {
    float v = fmaxf(agg[row * 64 + lane], 0.0f);
    float t0 = bd0, t1 = bd1;
#pragma unroll
    for (int k = 0; k < 64; ++k) {
      const float xk = __shfl(v, k);
      t0 = fmaf(xk, Wdl[k * 128 + lane], t0);
      t1 = fmaf(xk, Wdl[k * 128 + 64 + lane], t1);
    }
    t0 = fmaxf(t0, 0.0f);
    t1 = fmaxf(t1, 0.0f);
    float o0 = fmaf(t0, Wol[lane * 2 + 0], t1 * Wol[(lane + 64) * 2 + 0]);
    float o1 = fmaf(t0, Wol[lane * 2 + 1], t1 * Wol[(lane + 64) * 2 + 1]);
#pragma unroll
    for (int off = 32; off > 0; off >>= 1) {
      o0 += __shfl_down(o0, off);
      o1 += __shfl_down(o1, off);
    }
    if (lane == 0) {
      out[row * 2 + 0] = o0 + bo0;
      out[row * 2 + 1] = o1 + bo1;
    }
  }
}

extern "C" void kernel_launch(void* const* d_in, const int* in_sizes, int n_in,
                              void* d_out, int out_size, void* d_ws, size_t ws_size,
                              hipStream_t stream) {
  const float* x  = (const float*)d_in[0];
  const int*   ei = (const int*)d_in[1];
  const float* W1 = (const float*)d_in[2];
  const float* b1 = (const float*)d_in[3];
  const float* W2 = (const float*)d_in[4];
  const float* b2 = (const float*)d_in[5];
  const float* Wd = (const float*)d_in[6];
  const float* bd = (const float*)d_in[7];
  const float* Wo = (const float*)d_in[8];
  const float* bo = (const float*)d_in[9];
  float* out = (float*)d_out;

  const int* src = ei;        // edge_index[0]
  const int* dst = ei + NE;   // edge_index[1]

  float* ws   = (float*)d_ws;
  float* dis  = ws;                    // NN floats (deg counts, then rsqrt)
  float* bufH = ws + 100352;           // NN*64: h1, then h2
  float* bufG = bufH + NN * 64;        // NN*64: agg1, then agg2

  // degrees
  hipMemsetAsync(dis, 0, NN * sizeof(float), stream);
  k_count<<<(NE + 255) / 256, 256, 0, stream>>>(dst, dis);
  k_rsqrt_deg<<<(NN + 255) / 256, 256, 0, stream>>>(dis);

  // layer 1: h1 = x@W1 ; agg1 = h1*dis^2 + b1 ; agg1 += scatter
  k_mm64<false><<<4096, 256, 0, stream>>>(x, W1, b1, dis, bufH, bufG);
  k_scatter<<<8192, 256, 0, stream>>>(src, dst, dis, bufH, bufG);

  // layer 2: h2 = relu(agg1)@W2 ; agg2 = h2*dis^2 + b2 (in-place over agg1)
  k_mm64<true><<<4096, 256, 0, stream>>>(bufG, W2, b2, dis, bufH, bufG);
  k_scatter<<<8192, 256, 0, stream>>>(src, dst, dis, bufH, bufG);

  // head: relu -> dense(128) -> relu -> out(2)
  k_head<<<4096, 256, 0, stream>>>(bufG, Wd, bd, Wo, bo, out);
}

// Round 2
// 677.628 us; speedup vs baseline: 1.5194x; 1.5194x over previous
//
#include <hip/hip_runtime.h>

#define NN 100000
#define NE 1600000
#define NB 391  // ceil(NN/256) scan blocks

// ---------------- degree histogram ----------------
__global__ __launch_bounds__(256) void k_hist(const int* __restrict__ dst,
                                              int* __restrict__ cnt) {
  int i = blockIdx.x * 256 + threadIdx.x;
  if (i < NE) atomicAdd(&cnt[dst[i]], 1);
}

__global__ __launch_bounds__(256) void k_dis(const int* __restrict__ cnt,
                                             float* __restrict__ dis) {
  int i = blockIdx.x * 256 + threadIdx.x;
  if (i < NN) dis[i] = rsqrtf((float)cnt[i] + 1.0f);  // deg+1 (self loop)
}

// ---------------- 3-pass exclusive scan of cnt -> offs ----------------
__global__ __launch_bounds__(256) void k_scan1(const int* __restrict__ cnt,
                                               int* __restrict__ bsum) {
  __shared__ int s[256];
  int i = blockIdx.x * 256 + threadIdx.x;
  s[threadIdx.x] = (i < NN) ? cnt[i] : 0;
  __syncthreads();
  for (int off = 128; off; off >>= 1) {
    if (threadIdx.x < off) s[threadIdx.x] += s[threadIdx.x + off];
    __syncthreads();
  }
  if (threadIdx.x == 0) bsum[blockIdx.x] = s[0];
}

__global__ __launch_bounds__(512) void k_scan2(int* __restrict__ bsum) {
  __shared__ int s[512];
  int t = threadIdx.x;
  int orig = (t < NB) ? bsum[t] : 0;
  s[t] = orig;
  __syncthreads();
  for (int off = 1; off < 512; off <<= 1) {
    int v = (t >= off) ? s[t - off] : 0;
    __syncthreads();
    s[t] += v;
    __syncthreads();
  }
  if (t < NB) bsum[t] = s[t] - orig;  // exclusive
}

__global__ __launch_bounds__(256) void k_scan3(const int* __restrict__ cnt,
                                               const int* __restrict__ bofs,
                                               int* __restrict__ offs,
                                               int* __restrict__ cursor) {
  __shared__ int s[256];
  int i = blockIdx.x * 256 + threadIdx.x;
  int v = (i < NN) ? cnt[i] : 0;
  s[threadIdx.x] = v;
  __syncthreads();
  for (int off = 1; off < 256; off <<= 1) {
    int u = (threadIdx.x >= off) ? s[threadIdx.x - off] : 0;
    __syncthreads();
    s[threadIdx.x] += u;
    __syncthreads();
  }
  int excl = s[threadIdx.x] - v + bofs[blockIdx.x];
  if (i < NN) { offs[i] = excl; cursor[i] = excl; }
  if (i == 0) offs[NN] = NE;
}

// ---------------- bucket sort src ids by dst ----------------
__global__ __launch_bounds__(256) void k_sort(const int* __restrict__ src,
                                              const int* __restrict__ dst,
                                              int* __restrict__ cursor,
                                              int* __restrict__ srcs) {
  int i = blockIdx.x * 256 + threadIdx.x;
  if (i < NE) {
    int t = dst[i];
    int pos = atomicAdd(&cursor[t], 1);
    srcs[pos] = src[i];
  }
}

// ---------------- layer-1 GEMM: hs1 = (x @ W1) * dis ----------------
__global__ __launch_bounds__(256) void k_mm1(const float* __restrict__ in,
                                             const float* __restrict__ W,
                                             const float* __restrict__ dis,
                                             float* __restrict__ hs) {
  __shared__ float Wl[64 * 64];
  for (int i = threadIdx.x; i < 64 * 64; i += 256) Wl[i] = W[i];
  __syncthreads();
  const int lane = threadIdx.x & 63;
  const int gw = (blockIdx.x * 256 + threadIdx.x) >> 6;
  const int nw = gridDim.x * 4;
  for (int row = gw; row < NN; row += nw) {
    float v = in[row * 64 + lane];
    float acc = 0.0f;
#pragma unroll
    for (int k = 0; k < 64; ++k)
      acc = fmaf(__shfl(v, k), Wl[k * 64 + lane], acc);
    hs[row * 64 + lane] = acc * dis[row];
  }
}

// ---------------- gather + layer-2 GEMM fused ----------------
// agg1 = dis[t]*(sum_edges hs1[s] + hs1[t]) + b1 ; hs2 = (relu(agg1)@W2)*dis[t]
__global__ __launch_bounds__(256) void k_gmm(const float* __restrict__ hs_in,
                                             const int* __restrict__ offs,
                                             const int* __restrict__ srcs,
                                             const float* __restrict__ dis,
                                             const float* __restrict__ b,
                                             const float* __restrict__ W,
                                             float* __restrict__ hs_out) {
  __shared__ float Wl[64 * 64];
  for (int i = threadIdx.x; i < 64 * 64; i += 256) Wl[i] = W[i];
  __syncthreads();
  const int lane = threadIdx.x & 63;
  const int gw = (blockIdx.x * 256 + threadIdx.x) >> 6;
  const int nw = gridDim.x * 4;
  const float bl = b[lane];
  for (int t = gw; t < NN; t += nw) {
    float sum = hs_in[t * 64 + lane];  // self loop
    const int e1 = offs[t + 1];
    int e = offs[t];
    for (; e + 3 < e1; e += 4) {
      int s0 = srcs[e], s1 = srcs[e + 1], s2 = srcs[e + 2], s3 = srcs[e + 3];
      float a0 = hs_in[s0 * 64 + lane], a1 = hs_in[s1 * 64 + lane];
      float a2 = hs_in[s2 * 64 + lane], a3 = hs_in[s3 * 64 + lane];
      sum += (a0 + a1) + (a2 + a3);
    }
    for (; e < e1; ++e) sum += hs_in[srcs[e] * 64 + lane];
    const float d = dis[t];
    const float v = fmaxf(fmaf(d, sum, bl), 0.0f);
    float acc = 0.0f;
#pragma unroll
    for (int k = 0; k < 64; ++k)
      acc = fmaf(__shfl(v, k), Wl[k * 64 + lane], acc);
    hs_out[t * 64 + lane] = acc * d;
  }
}

// ---------------- gather + head fused ----------------
// agg2 = dis[t]*(sum hs2[s] + hs2[t]) + b2 ; relu -> dense128 -> relu -> out2
__global__ __launch_bounds__(256) void k_ghead(const float* __restrict__ hs_in,
                                               const int* __restrict__ offs,
                                               const int* __restrict__ srcs,
                                               const float* __restrict__ dis,
                                               const float* __restrict__ b,
                                               const float* __restrict__ Wd,
                                               const float* __restrict__ bd,
                                               const float* __restrict__ Wo,
                                               const float* __restrict__ bo,
                                               float* __restrict__ out) {
  __shared__ float Wdl[64 * 128];  // 32 KiB
  __shared__ float Wol[256];
  for (int i = threadIdx.x; i < 64 * 128; i += 256) Wdl[i] = Wd[i];
  if (threadIdx.x < 256) Wol[threadIdx.x] = Wo[threadIdx.x];
  __syncthreads();
  const int lane = threadIdx.x & 63;
  const int gw = (blockIdx.x * 256 + threadIdx.x) >> 6;
  const int nw = gridDim.x * 4;
  const float bl = b[lane];
  const float bd0 = bd[lane], bd1 = bd[lane + 64];
  const float bo0 = bo[0], bo1 = bo[1];
  for (int t = gw; t < NN; t += nw) {
    float sum = hs_in[t * 64 + lane];  // self loop
    const int e1 = offs[t + 1];
    int e = offs[t];
    for (; e + 3 < e1; e += 4) {
      int s0 = srcs[e], s1 = srcs[e + 1], s2 = srcs[e + 2], s3 = srcs[e + 3];
      float a0 = hs_in[s0 * 64 + lane], a1 = hs_in[s1 * 64 + lane];
      float a2 = hs_in[s2 * 64 + lane], a3 = hs_in[s3 * 64 + lane];
      sum += (a0 + a1) + (a2 + a3);
    }
    for (; e < e1; ++e) sum += hs_in[srcs[e] * 64 + lane];
    const float d = dis[t];
    const float v = fmaxf(fmaf(d, sum, bl), 0.0f);
    float t0 = bd0, t1 = bd1;
#pragma unroll
    for (int k = 0; k < 64; ++k) {
      const float xk = __shfl(v, k);
      t0 = fmaf(xk, Wdl[k * 128 + lane], t0);
      t1 = fmaf(xk, Wdl[k * 128 + 64 + lane], t1);
    }
    t0 = fmaxf(t0, 0.0f);
    t1 = fmaxf(t1, 0.0f);
    float o0 = fmaf(t0, Wol[lane * 2 + 0], t1 * Wol[(lane + 64) * 2 + 0]);
    float o1 = fmaf(t0, Wol[lane * 2 + 1], t1 * Wol[(lane + 64) * 2 + 1]);
#pragma unroll
    for (int off = 32; off > 0; off >>= 1) {
      o0 += __shfl_down(o0, off);
      o1 += __shfl_down(o1, off);
    }
    if (lane == 0) {
      out[t * 2 + 0] = o0 + bo0;
      out[t * 2 + 1] = o1 + bo1;
    }
  }
}

extern "C" void kernel_launch(void* const* d_in, const int* in_sizes, int n_in,
                              void* d_out, int out_size, void* d_ws, size_t ws_size,
                              hipStream_t stream) {
  const float* x  = (const float*)d_in[0];
  const int*   ei = (const int*)d_in[1];
  const float* W1 = (const float*)d_in[2];
  const float* b1 = (const float*)d_in[3];
  const float* W2 = (const float*)d_in[4];
  const float* b2 = (const float*)d_in[5];
  const float* Wd = (const float*)d_in[6];
  const float* bd = (const float*)d_in[7];
  const float* Wo = (const float*)d_in[8];
  const float* bo = (const float*)d_in[9];
  float* out = (float*)d_out;

  const int* src = ei;        // edge_index[0]
  const int* dst = ei + NE;   // edge_index[1]

  // workspace layout (4B elements)
  char* ws = (char*)d_ws;
  int*   cnt    = (int*)(ws);                       // NN (padded 102400)
  float* dis    = (float*)(ws + 102400 * 4);        // NN
  int*   bsum   = (int*)(ws + 204800 * 4);          // 512
  int*   offs   = (int*)(ws + 205312 * 4);          // NN+1 (padded 102400)
  int*   cursor = (int*)(ws + 307712 * 4);          // NN
  int*   srcs   = (int*)(ws + 410112 * 4);          // NE
  float* hs1    = (float*)(ws + 2010112L * 4);      // NN*64
  float* hs2    = (float*)(ws + 8410112L * 4);      // NN*64

  // CSR build (depends only on edge_index; reused by both layers)
  hipMemsetAsync(cnt, 0, NN * sizeof(int), stream);
  k_hist<<<(NE + 255) / 256, 256, 0, stream>>>(dst, cnt);
  k_dis<<<NB, 256, 0, stream>>>(cnt, dis);
  k_scan1<<<NB, 256, 0, stream>>>(cnt, bsum);
  k_scan2<<<1, 512, 0, stream>>>(bsum);
  k_scan3<<<NB, 256, 0, stream>>>(cnt, bsum, offs, cursor);
  k_sort<<<(NE + 255) / 256, 256, 0, stream>>>(src, dst, cursor, srcs);

  // layer 1 GEMM
  k_mm1<<<4096, 256, 0, stream>>>(x, W1, dis, hs1);
  // gather-1 + layer-2 GEMM fused
  k_gmm<<<4096, 256, 0, stream>>>(hs1, offs, srcs, dis, b1, W2, hs2);
  // gather-2 + dense head fused
  k_ghead<<<4096, 256, 0, stream>>>(hs2, offs, srcs, dis, b2, Wd, bd, Wo, bo, out);
}

// Round 3
// 606.355 us; speedup vs baseline: 1.6980x; 1.1175x over previous
//
#include <hip/hip_runtime.h>

#define NN 100000
#define NE 1600000
#define NB 391  // ceil(NN/256) scan blocks

// ---------------- degree histogram ----------------
__global__ __launch_bounds__(256) void k_hist(const int* __restrict__ dst,
                                              int* __restrict__ cnt) {
  int i = blockIdx.x * 256 + threadIdx.x;
  if (i < NE) atomicAdd(&cnt[dst[i]], 1);
}

__global__ __launch_bounds__(256) void k_dis(const int* __restrict__ cnt,
                                             float* __restrict__ dis) {
  int i = blockIdx.x * 256 + threadIdx.x;
  if (i < NN) dis[i] = rsqrtf((float)cnt[i] + 1.0f);  // deg+1 (self loop)
}

// ---------------- 3-pass exclusive scan of cnt -> offs ----------------
__global__ __launch_bounds__(256) void k_scan1(const int* __restrict__ cnt,
                                               int* __restrict__ bsum) {
  __shared__ int s[256];
  int i = blockIdx.x * 256 + threadIdx.x;
  s[threadIdx.x] = (i < NN) ? cnt[i] : 0;
  __syncthreads();
  for (int off = 128; off; off >>= 1) {
    if (threadIdx.x < off) s[threadIdx.x] += s[threadIdx.x + off];
    __syncthreads();
  }
  if (threadIdx.x == 0) bsum[blockIdx.x] = s[0];
}

__global__ __launch_bounds__(512) void k_scan2(int* __restrict__ bsum) {
  __shared__ int s[512];
  int t = threadIdx.x;
  int orig = (t < NB) ? bsum[t] : 0;
  s[t] = orig;
  __syncthreads();
  for (int off = 1; off < 512; off <<= 1) {
    int v = (t >= off) ? s[t - off] : 0;
    __syncthreads();
    s[t] += v;
    __syncthreads();
  }
  if (t < NB) bsum[t] = s[t] - orig;  // exclusive
}

__global__ __launch_bounds__(256) void k_scan3(const int* __restrict__ cnt,
                                               const int* __restrict__ bofs,
                                               int* __restrict__ offs,
                                               int* __restrict__ cursor) {
  __shared__ int s[256];
  int i = blockIdx.x * 256 + threadIdx.x;
  int v = (i < NN) ? cnt[i] : 0;
  s[threadIdx.x] = v;
  __syncthreads();
  for (int off = 1; off < 256; off <<= 1) {
    int u = (threadIdx.x >= off) ? s[threadIdx.x - off] : 0;
    __syncthreads();
    s[threadIdx.x] += u;
    __syncthreads();
  }
  int excl = s[threadIdx.x] - v + bofs[blockIdx.x];
  if (i < NN) { offs[i] = excl; cursor[i] = excl; }
  if (i == 0) offs[NN] = NE;
}

// ---------------- bucket sort src ids by dst ----------------
__global__ __launch_bounds__(256) void k_sort(const int* __restrict__ src,
                                              const int* __restrict__ dst,
                                              int* __restrict__ cursor,
                                              int* __restrict__ srcs) {
  int i = blockIdx.x * 256 + threadIdx.x;
  if (i < NE) {
    int t = dst[i];
    int pos = atomicAdd(&cursor[t], 1);
    srcs[pos] = src[i];
  }
}

// ---------------- 64x64 GEMM: hs = (in @ W) * dis ----------------
__global__ __launch_bounds__(256) void k_mm(const float* __restrict__ in,
                                            const float* __restrict__ W,
                                            const float* __restrict__ dis,
                                            float* __restrict__ hs) {
  __shared__ float Wl[64 * 64];
  for (int i = threadIdx.x; i < 64 * 64; i += 256) Wl[i] = W[i];
  __syncthreads();
  const int lane = threadIdx.x & 63;
  const int gw = (blockIdx.x * 256 + threadIdx.x) >> 6;
  const int nw = gridDim.x * 4;
  for (int row = gw; row < NN; row += nw) {
    float v = in[row * 64 + lane];
    float acc = 0.0f;
#pragma unroll
    for (int k = 0; k < 64; ++k)
      acc = fmaf(__shfl(v, k), Wl[k * 64 + lane], acc);
    hs[row * 64 + lane] = acc * dis[row];
  }
}

// ---------------- pure gather: v = relu(dis[t]*(self + sum_edges) + b) ----
// No LDS, low VGPR, unroll-8 -> high occupancy + deep MLP.
__global__ __launch_bounds__(256) void k_gather(const float* __restrict__ hs_in,
                                                const int* __restrict__ offs,
                                                const int* __restrict__ srcs,
                                                const float* __restrict__ dis,
                                                const float* __restrict__ b,
                                                float* __restrict__ v_out) {
  const int lane = threadIdx.x & 63;
  const int gw = (blockIdx.x * 256 + threadIdx.x) >> 6;
  const int nw = gridDim.x * 4;
  const float bl = b[lane];
  for (int t = gw; t < NN; t += nw) {
    float sum = hs_in[t * 64 + lane];  // self loop
    const int e1 = offs[t + 1];
    int e = offs[t];
    for (; e + 8 <= e1; e += 8) {
      float a0 = hs_in[srcs[e + 0] * 64 + lane];
      float a1 = hs_in[srcs[e + 1] * 64 + lane];
      float a2 = hs_in[srcs[e + 2] * 64 + lane];
      float a3 = hs_in[srcs[e + 3] * 64 + lane];
      float a4 = hs_in[srcs[e + 4] * 64 + lane];
      float a5 = hs_in[srcs[e + 5] * 64 + lane];
      float a6 = hs_in[srcs[e + 6] * 64 + lane];
      float a7 = hs_in[srcs[e + 7] * 64 + lane];
      sum += ((a0 + a1) + (a2 + a3)) + ((a4 + a5) + (a6 + a7));
    }
    for (; e < e1; ++e) sum += hs_in[srcs[e] * 64 + lane];
    v_out[t * 64 + lane] = fmaxf(fmaf(dis[t], sum, bl), 0.0f);
  }
}

// ---------------- dense head: v2 -> relu(dense128) -> out2 ----------------
__global__ __launch_bounds__(256) void k_head(const float* __restrict__ v2,
                                              const float* __restrict__ Wd,
                                              const float* __restrict__ bd,
                                              const float* __restrict__ Wo,
                                              const float* __restrict__ bo,
                                              float* __restrict__ out) {
  __shared__ float Wdl[64 * 128];  // 32 KiB
  __shared__ float Wol[256];
  for (int i = threadIdx.x; i < 64 * 128; i += 256) Wdl[i] = Wd[i];
  if (threadIdx.x < 256) Wol[threadIdx.x] = Wo[threadIdx.x];
  __syncthreads();
  const int lane = threadIdx.x & 63;
  const int gw = (blockIdx.x * 256 + threadIdx.x) >> 6;
  const int nw = gridDim.x * 4;
  const float bd0 = bd[lane], bd1 = bd[lane + 64];
  const float bo0 = bo[0], bo1 = bo[1];
  for (int row = gw; row < NN; row += nw) {
    float v = v2[row * 64 + lane];  // already relu'd
    float t0 = bd0, t1 = bd1;
#pragma unroll
    for (int k = 0; k < 64; ++k) {
      const float xk = __shfl(v, k);
      t0 = fmaf(xk, Wdl[k * 128 + lane], t0);
      t1 = fmaf(xk, Wdl[k * 128 + 64 + lane], t1);
    }
    t0 = fmaxf(t0, 0.0f);
    t1 = fmaxf(t1, 0.0f);
    float o0 = fmaf(t0, Wol[lane * 2 + 0], t1 * Wol[(lane + 64) * 2 + 0]);
    float o1 = fmaf(t0, Wol[lane * 2 + 1], t1 * Wol[(lane + 64) * 2 + 1]);
#pragma unroll
    for (int off = 32; off > 0; off >>= 1) {
      o0 += __shfl_down(o0, off);
      o1 += __shfl_down(o1, off);
    }
    if (lane == 0) {
      out[row * 2 + 0] = o0 + bo0;
      out[row * 2 + 1] = o1 + bo1;
    }
  }
}

extern "C" void kernel_launch(void* const* d_in, const int* in_sizes, int n_in,
                              void* d_out, int out_size, void* d_ws, size_t ws_size,
                              hipStream_t stream) {
  const float* x  = (const float*)d_in[0];
  const int*   ei = (const int*)d_in[1];
  const float* W1 = (const float*)d_in[2];
  const float* b1 = (const float*)d_in[3];
  const float* W2 = (const float*)d_in[4];
  const float* b2 = (const float*)d_in[5];
  const float* Wd = (const float*)d_in[6];
  const float* bd = (const float*)d_in[7];
  const float* Wo = (const float*)d_in[8];
  const float* bo = (const float*)d_in[9];
  float* out = (float*)d_out;

  const int* src = ei;        // edge_index[0]
  const int* dst = ei + NE;   // edge_index[1]

  // workspace layout (4B elements)
  char* ws = (char*)d_ws;
  int*   cnt    = (int*)(ws);                       // NN (padded 102400)
  float* dis    = (float*)(ws + 102400 * 4);        // NN
  int*   bsum   = (int*)(ws + 204800 * 4);          // 512
  int*   offs   = (int*)(ws + 205312 * 4);          // NN+1 (padded 102400)
  int*   cursor = (int*)(ws + 307712 * 4);          // NN
  int*   srcs   = (int*)(ws + 410112 * 4);          // NE
  float* bufA   = (float*)(ws + 2010112L * 4);      // NN*64: hs1, then hs2
  float* bufB   = (float*)(ws + 8410112L * 4);      // NN*64: v1, then v2

  // CSR build (depends only on edge_index; reused by both layers)
  hipMemsetAsync(cnt, 0, NN * sizeof(int), stream);
  k_hist<<<(NE + 255) / 256, 256, 0, stream>>>(dst, cnt);
  k_dis<<<NB, 256, 0, stream>>>(cnt, dis);
  k_scan1<<<NB, 256, 0, stream>>>(cnt, bsum);
  k_scan2<<<1, 512, 0, stream>>>(bsum);
  k_scan3<<<NB, 256, 0, stream>>>(cnt, bsum, offs, cursor);
  k_sort<<<(NE + 255) / 256, 256, 0, stream>>>(src, dst, cursor, srcs);

  // layer 1: hs1 = (x@W1)*dis ; v1 = relu(dis*(gather hs1)+b1)
  k_mm<<<4096, 256, 0, stream>>>(x, W1, dis, bufA);
  k_gather<<<4096, 256, 0, stream>>>(bufA, offs, srcs, dis, b1, bufB);
  // layer 2: hs2 = (v1@W2)*dis ; v2 = relu(dis*(gather hs2)+b2)
  k_mm<<<4096, 256, 0, stream>>>(bufB, W2, dis, bufA);
  k_gather<<<4096, 256, 0, stream>>>(bufA, offs, srcs, dis, b2, bufB);
  // head: dense(128) -> relu -> out(2)
  k_head<<<4096, 256, 0, stream>>>(bufB, Wd, bd, Wo, bo, out);
}